// Round 5
// baseline (1500.033 us; speedup 1.0000x reference)
//
#include <hip/hip_runtime.h>
#include <hip/hip_bf16.h>
#include <stdint.h>

// out[b,t,k,f] = sum_d x[b,t,d] * (qw[k,d,f]-qz[k,d/128,f])*sc[k,d/128,f]
// Stage 1: build swizzled bf16 panels in d_ws (A: [m_half][kt], B^T: [n_half][kt],
//          16KB panels, byte (r*128+c*2)^((r&7)<<4)).
// Stage 2: 256x256x64 8-phase double-buffered MFMA GEMM.
// R5: register read-ahead — phase p ds_reads phase p+1's fragments, so the LDS
// drain overlaps the MFMA cluster (R4 serialized them: 2304+2483 cyc/K-tile).
// One barrier per phase (region ledger verified disjoint at skew 1).

typedef __attribute__((ext_vector_type(8))) short bf16x8;
typedef __attribute__((ext_vector_type(4))) float f32x4;

static constexpr int Dd = 4096, Ff = 8192;
static constexpr int M = 8192, NTOT = 16384;
static constexpr int NKT = Dd / 64;       // 64 K-tiles
static constexpr int NMB = M / 256;       // 32
static constexpr int NNB = NTOT / 256;    // 64

__device__ __forceinline__ short f2bf(float f) {
    __hip_bfloat16 h = __float2bfloat16(f);
    return *reinterpret_cast<short*>(&h);
}

// ---------------- Stage 1a: x fp32 -> swizzled bf16 A-panels ----------------
__global__ __launch_bounds__(256) void xcvt(const float* __restrict__ x,
                                            char* __restrict__ Xw) {
    const int bid = blockIdx.x;             // h*64 + kt, h in [0,64)
    const int h = bid >> 6, kt = bid & 63;
    const int t = threadIdx.x;
    const int r = t >> 1, seg = t & 1;
    const float* src = x + ((size_t)(h * 128 + r)) * Dd + kt * 64 + seg * 32;
    char* panel = Xw + ((size_t)bid << 14);
    #pragma unroll
    for (int jj = 0; jj < 4; ++jj) {
        float4 v0 = *reinterpret_cast<const float4*>(src + jj * 8);
        float4 v1 = *reinterpret_cast<const float4*>(src + jj * 8 + 4);
        union { short s[8]; bf16x8 v; } u;
        u.s[0] = f2bf(v0.x); u.s[1] = f2bf(v0.y); u.s[2] = f2bf(v0.z); u.s[3] = f2bf(v0.w);
        u.s[4] = f2bf(v1.x); u.s[5] = f2bf(v1.y); u.s[6] = f2bf(v1.z); u.s[7] = f2bf(v1.w);
        const int cb = seg * 4 + jj;
        const int g = r * 8 + (cb ^ (r & 7));
        *reinterpret_cast<bf16x8*>(panel + g * 16) = u.v;
    }
}

// ---------------- Stage 1b: dequant int4 -> swizzled bf16 B^T panels ----------------
__global__ __launch_bounds__(256) void wdq(const int* __restrict__ qw,
                                           const int* __restrict__ qz,
                                           const float* __restrict__ sc,
                                           char* __restrict__ Ww) {
    const int bid = blockIdx.x;             // fh*64 + kt, fh in [0,128)
    const int fh = bid >> 6, kt = bid & 63;
    const int t = threadIdx.x;
    const int r = t & 127, dh = t >> 7;
    const int n = fh * 128 + r;
    const int k = n >> 13, f = n & 8191;
    const int g = kt >> 1;                  // 64-col tile within one 128-group
    const int   zv = qz[((size_t)k * 32 + g) * Ff + f];
    const float sv = sc[((size_t)k * 32 + g) * Ff + f];
    const int* qp = qw + ((size_t)(k * Dd + kt * 64 + dh * 32)) * Ff + f;
    char* panel = Ww + ((size_t)bid << 14);
    #pragma unroll
    for (int jj = 0; jj < 4; ++jj) {
        union { short s[8]; bf16x8 v; } u;
        #pragma unroll
        for (int e = 0; e < 8; ++e) {
            int q = qp[(size_t)(jj * 8 + e) * Ff];
            u.s[e] = f2bf((float)(q - zv) * sv);
        }
        const int cb = dh * 4 + jj;
        const int gi = r * 8 + (cb ^ (r & 7));
        *reinterpret_cast<bf16x8*>(panel + gi * 16) = u.v;
    }
}

// ---------------- Stage 2: 256x256 8-phase GEMM with register read-ahead ----------------
#define APAN(HALF, KT) (Xw + (((size_t)(bm2 + (HALF)) * 64 + (KT)) << 14))
#define BPAN(HALF, KT) (Ww + (((size_t)(bn2 + (HALF)) * 64 + (KT)) << 14))

#define STAGE(GP, LP) do {                                                         \
    const char* _g = (GP) + woff16;                                                \
    char* _l = (LP) + woffu;                                                       \
    __builtin_amdgcn_global_load_lds(                                              \
        (const __attribute__((address_space(1))) void*)(_g),                       \
        (__attribute__((address_space(3))) void*)(_l), 16, 0, 0);                  \
    __builtin_amdgcn_global_load_lds(                                              \
        (const __attribute__((address_space(1))) void*)(_g + 8192),                \
        (__attribute__((address_space(3))) void*)(_l + 8192), 16, 0, 0);           \
} while (0)

// swizzled LDS read of one MFMA fragment (16B)
#define RDF(BASE, R, CB) \
    (*reinterpret_cast<const bf16x8*>((BASE) + ((((R) << 7) + (CB)) ^ (((R) & 7) << 4))))

// read next-phase A fragments (4 x ds_read_b128)
#define RDA(DST, LA, H, KK) do {                                                   \
    _Pragma("unroll")                                                              \
    for (int j = 0; j < 4; ++j)                                                    \
        DST[j] = RDF((LA) + apan, ((H) * 4 + j) * 16 + l15, (KK) * 2 + lhi16);     \
} while (0)

// read next-phase B fragments (4 x ds_read_b128)
#define RDB(DST, LB, KK) do {                                                      \
    _Pragma("unroll")                                                              \
    for (int ni = 0; ni < 4; ++ni)                                                 \
        DST[ni] = RDF((LB) + bpan, brow + ni * 16, (KK) * 2 + lhi16);              \
} while (0)

// MFMA cluster on current fragments (16 MFMA)
#define MM(H, AF, BB) do {                                                         \
    __builtin_amdgcn_sched_barrier(0);                                             \
    __builtin_amdgcn_s_setprio(1);                                                 \
    _Pragma("unroll")                                                              \
    for (int j = 0; j < 4; ++j)                                                    \
        _Pragma("unroll")                                                          \
        for (int ni = 0; ni < 4; ++ni)                                             \
            acc[(H) * 4 + j][ni] = __builtin_amdgcn_mfma_f32_16x16x32_bf16(        \
                AF[j], BB[ni], acc[(H) * 4 + j][ni], 0, 0, 0);                     \
    __builtin_amdgcn_s_setprio(0);                                                 \
    __builtin_amdgcn_sched_barrier(0);                                             \
} while (0)

#define BAR() do {                                                                 \
    __builtin_amdgcn_sched_barrier(0);                                             \
    __builtin_amdgcn_s_barrier();                                                  \
} while (0)

__global__ __launch_bounds__(512, 2) void gemm256(const char* __restrict__ Xw,
                                                  const char* __restrict__ Ww,
                                                  float* __restrict__ out) {
    __shared__ char lds[131072];
    char* lA0 = lds;
    char* lB0 = lds + 32768;
    char* lA1 = lds + 65536;
    char* lB1 = lds + 98304;

    const int t = threadIdx.x;
    const int wave = t >> 6, lane = t & 63;
    const int wm = wave >> 2, wn = wave & 3;      // 2 x 4 waves
    const int l15 = lane & 15, lhi16 = (lane >> 4) * 16;

    // bijective XCD swizzle (2048 % 8 == 0); the 32 concurrent blocks per XCD
    // share one 4MB B slab (L2-resident) and span all bm (A L3-resident)
    const int xcd = blockIdx.x & 7;
    const int c   = blockIdx.x >> 3;              // 0..255
    const int bn  = xcd * 8 + (c >> 5);           // 0..63
    const int bm  = c & 31;                       // 0..31
    const int bm2 = bm * 2, bn2 = bn * 2;

    const int woff16 = wave * 1024 + lane * 16;   // per-lane global offset
    const int woffu  = wave * 1024;               // wave-uniform LDS offset
    const int apan = wm * 16384;                  // wave's A half-panel
    const int bpan = (wn >> 1) * 16384;           // wave's B half-panel
    const int brow = (wn & 1) * 64 + l15;         // B row base within panel

    bf16x8 af0[4], af1[4], bb0[4], bb1[4];
    f32x4 acc[8][4] = {};

    // prologue: tile0 (4 halves) + tile1.B0; wait tile0; read P1 fragments
    STAGE(APAN(0, 0), lA0);
    STAGE(APAN(1, 0), lA0 + 16384);
    STAGE(BPAN(0, 0), lB0);
    STAGE(BPAN(1, 0), lB0 + 16384);
    STAGE(BPAN(0, 1), lB1);
    asm volatile("s_waitcnt vmcnt(2)" ::: "memory");
    BAR();
    RDB(bb0, lB0, 0);
    RDA(af0, lA0, 0, 0);

    for (int i = 0; i < 32; ++i) {
        const int kt0 = 2 * i;
        const bool nl = (i < 31);
        // P1: MFMA(buf0,H0,K0); read P2 frags; stage B1(T+1)
        STAGE(BPAN(1, kt0 + 1), lB1 + 16384);
        BAR();
        RDA(af1, lA0, 1, 0);
        MM(0, af0, bb0);
        // P2: MFMA(buf0,H1,K0); read P3 frags (K32)
        STAGE(APAN(0, kt0 + 1), lA1);
        BAR();
        RDB(bb1, lB0, 32);
        RDA(af0, lA0, 0, 32);
        MM(1, af1, bb0);
        // P3
        STAGE(APAN(1, kt0 + 1), lA1 + 16384);
        BAR();
        RDA(af1, lA0, 1, 32);
        MM(0, af0, bb1);
        // P4: vmcnt certifies tile T+1 (buf1) landed before reading it
        if (nl) {
            STAGE(BPAN(0, kt0 + 2), lB0);
            asm volatile("s_waitcnt vmcnt(2)" ::: "memory");
        } else {
            asm volatile("s_waitcnt vmcnt(0)" ::: "memory");
        }
        BAR();
        RDB(bb0, lB1, 0);
        RDA(af0, lA1, 0, 0);
        MM(1, af1, bb1);
        // P5
        if (nl) STAGE(BPAN(1, kt0 + 2), lB0 + 16384);
        BAR();
        RDA(af1, lA1, 1, 0);
        MM(0, af0, bb0);
        // P6
        if (nl) STAGE(APAN(0, kt0 + 2), lA0);
        BAR();
        RDB(bb1, lB1, 32);
        RDA(af0, lA1, 0, 32);
        MM(1, af1, bb0);
        // P7
        if (nl) STAGE(APAN(1, kt0 + 2), lA0 + 16384);
        BAR();
        RDA(af1, lA1, 1, 32);
        MM(0, af0, bb1);
        // P8: vmcnt certifies tile T+2 (buf0) landed before reading it
        if (nl) {
            STAGE(BPAN(0, kt0 + 3), lB1);
            asm volatile("s_waitcnt vmcnt(2)" ::: "memory");
        }
        BAR();
        RDB(bb0, lB0, 0);   // last iter: stale data, results unused
        RDA(af0, lA0, 0, 0);
        MM(1, af1, bb1);
    }

    // epilogue: C/D layout col=lane&15, row=(lane>>4)*4+reg
    const int gr0 = bm * 256 + wm * 128 + (lhi16 >> 2);
    const int gc0 = bn * 256 + wn * 64 + l15;
    #pragma unroll
    for (int mi = 0; mi < 8; ++mi)
        #pragma unroll
        for (int ni = 0; ni < 4; ++ni)
            #pragma unroll
            for (int rr = 0; rr < 4; ++rr)
                out[(size_t)(gr0 + mi * 16 + rr) * NTOT + gc0 + ni * 16] =
                    acc[mi][ni][rr];
}

// ---------------- Fallback (ws too small): round-1 fused kernel ----------------
#define LDP 72
__global__ __launch_bounds__(256) void int4_gemm(
    const float* __restrict__ x, const int* __restrict__ qw,
    const int* __restrict__ qz, const float* __restrict__ sc,
    float* __restrict__ out)
{
    __shared__ short As[128][LDP];
    __shared__ short Bs[128][LDP];
    const int t = threadIdx.x;
    int gid = (blockIdx.x & 7) * 1024 + (blockIdx.x >> 3);
    const int bm = gid & 63;
    const int bnq = gid >> 6;
    const int kse = bnq >> 6;
    const int f0  = (bnq & 63) * 128;
    const int m0  = bm * 128;
    const int wave = t >> 6, lane = t & 63;
    const int wm = wave >> 1, wn = wave & 1;
    const int l15 = lane & 15, lhi = lane >> 4;
    const int am = t >> 4, ad = (t & 15) * 4;
    const int bf = t & 127, bd = (t >> 7) * 4;
    const int*   qwk = qw + (size_t)kse * Dd * Ff;
    const int*   qzk = qz + (size_t)kse * 32 * Ff;
    const float* sck = sc + (size_t)kse * 32 * Ff;
    f32x4 acc[4][4] = {};
    for (int d0 = 0; d0 < Dd; d0 += 64) {
        __syncthreads();
        #pragma unroll
        for (int p = 0; p < 8; ++p) {
            int m = p * 16 + am;
            const float4 v = *reinterpret_cast<const float4*>(
                &x[(size_t)(m0 + m) * Dd + d0 + ad]);
            short4 wv;
            wv.x = f2bf(v.x); wv.y = f2bf(v.y); wv.z = f2bf(v.z); wv.w = f2bf(v.w);
            *reinterpret_cast<short4*>(&As[m][ad]) = wv;
        }
        {
            const int g = d0 >> 7;
            const int   zv = qzk[g * Ff + f0 + bf];
            const float sv = sck[g * Ff + f0 + bf];
            #pragma unroll
            for (int p = 0; p < 8; ++p) {
                int dl = p * 8 + bd;
                const int* qp = qwk + (size_t)(d0 + dl) * Ff + f0 + bf;
                short4 wv;
                wv.x = f2bf((float)(qp[0]      - zv) * sv);
                wv.y = f2bf((float)(qp[Ff]     - zv) * sv);
                wv.z = f2bf((float)(qp[2 * Ff] - zv) * sv);
                wv.w = f2bf((float)(qp[3 * Ff] - zv) * sv);
                *reinterpret_cast<short4*>(&Bs[bf][dl]) = wv;
            }
        }
        __syncthreads();
        #pragma unroll
        for (int kk = 0; kk < 64; kk += 32) {
            bf16x8 a2[4], b2[4];
            #pragma unroll
            for (int i = 0; i < 4; ++i)
                a2[i] = *reinterpret_cast<const bf16x8*>(&As[wm * 64 + i * 16 + l15][kk + lhi * 8]);
            #pragma unroll
            for (int i = 0; i < 4; ++i)
                b2[i] = *reinterpret_cast<const bf16x8*>(&Bs[wn * 64 + i * 16 + l15][kk + lhi * 8]);
            #pragma unroll
            for (int mi = 0; mi < 4; ++mi)
                #pragma unroll
                for (int ni = 0; ni < 4; ++ni)
                    acc[mi][ni] = __builtin_amdgcn_mfma_f32_16x16x32_bf16(
                        a2[mi], b2[ni], acc[mi][ni], 0, 0, 0);
        }
    }
    const int crow0 = m0 + wm * 64 + lhi * 4;
    const int ccol0 = bnq * 128 + wn * 64 + l15;
    #pragma unroll
    for (int mi = 0; mi < 4; ++mi)
        #pragma unroll
        for (int ni = 0; ni < 4; ++ni)
            #pragma unroll
            for (int r = 0; r < 4; ++r)
                out[(size_t)(crow0 + mi * 16 + r) * NTOT + ccol0 + ni * 16] =
                    acc[mi][ni][r];
}

extern "C" void kernel_launch(void* const* d_in, const int* in_sizes, int n_in,
                              void* d_out, int out_size, void* d_ws, size_t ws_size,
                              hipStream_t stream) {
    const float* x  = (const float*)d_in[0];
    const int*   qw = (const int*)d_in[1];
    const int*   qz = (const int*)d_in[2];
    const float* sc = (const float*)d_in[3];
    float*       out = (float*)d_out;

    const size_t xw_bytes = (size_t)(M / 128) * NKT * 16384;      // 64 MiB
    const size_t ww_bytes = (size_t)(NTOT / 128) * NKT * 16384;   // 128 MiB

    if (ws_size >= xw_bytes + ww_bytes) {
        char* Xw = (char*)d_ws;
        char* Ww = Xw + xw_bytes;
        hipLaunchKernelGGL(xcvt, dim3((M / 128) * NKT), dim3(256), 0, stream, x, Xw);
        hipLaunchKernelGGL(wdq, dim3((NTOT / 128) * NKT), dim3(256), 0, stream,
                           qw, qz, sc, Ww);
        hipLaunchKernelGGL(gemm256, dim3(NMB * NNB), dim3(512), 0, stream,
                           Xw, Ww, out);
    } else {
        hipLaunchKernelGGL(int4_gemm, dim3(8192), dim3(256), 0, stream,
                           x, qw, qz, sc, out);
    }
}

// Round 6
// 1475.530 us; speedup vs baseline: 1.0166x; 1.0166x over previous
//
#include <hip/hip_runtime.h>
#include <hip/hip_bf16.h>
#include <stdint.h>

// out[b,t,k,f] = sum_d x[b,t,d] * (qw[k,d,f]-qz[k,d/128,f])*sc[k,d/128,f]
// Stage 1: build swizzled bf16 panels in d_ws (A: [m_half][kt], B^T: [n_half][kt],
//          16KB panels, byte (r*128+c*2)^((r&7)<<4)).
// Stage 2: 256x256x64 MFMA GEMM, ONE barrier per K-tile:
//   issue fragment ds_reads early, stage next tile into the other buffer,
//   run 4 MFMA clusters behind compiler-counted lgkm waits (LDS drain
//   overlaps MFMA), vmcnt(0)+s_barrier only at the tile boundary.
// R5 lesson: per-phase barriers lock all waves into the same phase, forcing
// LDS-burst and MFMA-burst to alternate (serial sum = measured 1030 us).

typedef __attribute__((ext_vector_type(8))) short bf16x8;
typedef __attribute__((ext_vector_type(4))) float f32x4;

static constexpr int Dd = 4096, Ff = 8192;
static constexpr int M = 8192, NTOT = 16384;
static constexpr int NKT = Dd / 64;       // 64 K-tiles
static constexpr int NMB = M / 256;       // 32
static constexpr int NNB = NTOT / 256;    // 64

__device__ __forceinline__ short f2bf(float f) {
    __hip_bfloat16 h = __float2bfloat16(f);
    return *reinterpret_cast<short*>(&h);
}

// ---------------- Stage 1a: x fp32 -> swizzled bf16 A-panels ----------------
__global__ __launch_bounds__(256) void xcvt(const float* __restrict__ x,
                                            char* __restrict__ Xw) {
    const int bid = blockIdx.x;             // h*64 + kt, h in [0,64)
    const int h = bid >> 6, kt = bid & 63;
    const int t = threadIdx.x;
    const int r = t >> 1, seg = t & 1;
    const float* src = x + ((size_t)(h * 128 + r)) * Dd + kt * 64 + seg * 32;
    char* panel = Xw + ((size_t)bid << 14);
    #pragma unroll
    for (int jj = 0; jj < 4; ++jj) {
        float4 v0 = *reinterpret_cast<const float4*>(src + jj * 8);
        float4 v1 = *reinterpret_cast<const float4*>(src + jj * 8 + 4);
        union { short s[8]; bf16x8 v; } u;
        u.s[0] = f2bf(v0.x); u.s[1] = f2bf(v0.y); u.s[2] = f2bf(v0.z); u.s[3] = f2bf(v0.w);
        u.s[4] = f2bf(v1.x); u.s[5] = f2bf(v1.y); u.s[6] = f2bf(v1.z); u.s[7] = f2bf(v1.w);
        const int cb = seg * 4 + jj;
        const int g = r * 8 + (cb ^ (r & 7));
        *reinterpret_cast<bf16x8*>(panel + g * 16) = u.v;
    }
}

// ---------------- Stage 1b: dequant int4 -> swizzled bf16 B^T panels ----------------
__global__ __launch_bounds__(256) void wdq(const int* __restrict__ qw,
                                           const int* __restrict__ qz,
                                           const float* __restrict__ sc,
                                           char* __restrict__ Ww) {
    const int bid = blockIdx.x;             // fh*64 + kt, fh in [0,128)
    const int fh = bid >> 6, kt = bid & 63;
    const int t = threadIdx.x;
    const int r = t & 127, dh = t >> 7;
    const int n = fh * 128 + r;
    const int k = n >> 13, f = n & 8191;
    const int g = kt >> 1;                  // 64-col tile within one 128-group
    const int   zv = qz[((size_t)k * 32 + g) * Ff + f];
    const float sv = sc[((size_t)k * 32 + g) * Ff + f];
    const int* qp = qw + ((size_t)(k * Dd + kt * 64 + dh * 32)) * Ff + f;
    char* panel = Ww + ((size_t)bid << 14);
    #pragma unroll
    for (int jj = 0; jj < 4; ++jj) {
        union { short s[8]; bf16x8 v; } u;
        #pragma unroll
        for (int e = 0; e < 8; ++e) {
            int q = qp[(size_t)(jj * 8 + e) * Ff];
            u.s[e] = f2bf((float)(q - zv) * sv);
        }
        const int cb = dh * 4 + jj;
        const int gi = r * 8 + (cb ^ (r & 7));
        *reinterpret_cast<bf16x8*>(panel + gi * 16) = u.v;
    }
}

// ---------------- Stage 2: 256x256 GEMM, 1 barrier per K-tile ----------------
#define APAN(HALF, KT) (Xw + (((size_t)(bm2 + (HALF)) * 64 + (KT)) << 14))
#define BPAN(HALF, KT) (Ww + (((size_t)(bn2 + (HALF)) * 64 + (KT)) << 14))

#define STAGE(GP, LP) do {                                                         \
    const char* _g = (GP) + woff16;                                                \
    char* _l = (LP) + woffu;                                                       \
    __builtin_amdgcn_global_load_lds(                                              \
        (const __attribute__((address_space(1))) void*)(_g),                       \
        (__attribute__((address_space(3))) void*)(_l), 16, 0, 0);                  \
    __builtin_amdgcn_global_load_lds(                                              \
        (const __attribute__((address_space(1))) void*)(_g + 8192),                \
        (__attribute__((address_space(3))) void*)(_l + 8192), 16, 0, 0);           \
} while (0)

// swizzled LDS read of one MFMA fragment (16B)
#define RDF(BASE, R, CB) \
    (*reinterpret_cast<const bf16x8*>((BASE) + ((((R) << 7) + (CB)) ^ (((R) & 7) << 4))))

#define RDA(DST, LA, H, KK) do {                                                   \
    _Pragma("unroll")                                                              \
    for (int j = 0; j < 4; ++j)                                                    \
        DST[j] = RDF((LA) + apan, ((H) * 4 + j) * 16 + l15, (KK) * 2 + lhi16);     \
} while (0)

#define RDB(DST, LB, KK) do {                                                      \
    _Pragma("unroll")                                                              \
    for (int ni = 0; ni < 4; ++ni)                                                 \
        DST[ni] = RDF((LB) + bpan, brow + ni * 16, (KK) * 2 + lhi16);              \
} while (0)

#define MM(H, AF, BB) do {                                                         \
    __builtin_amdgcn_sched_barrier(0);                                             \
    __builtin_amdgcn_s_setprio(1);                                                 \
    _Pragma("unroll")                                                              \
    for (int j = 0; j < 4; ++j)                                                    \
        _Pragma("unroll")                                                          \
        for (int ni = 0; ni < 4; ++ni)                                             \
            acc[(H) * 4 + j][ni] = __builtin_amdgcn_mfma_f32_16x16x32_bf16(        \
                AF[j], BB[ni], acc[(H) * 4 + j][ni], 0, 0, 0);                     \
    __builtin_amdgcn_s_setprio(0);                                                 \
    __builtin_amdgcn_sched_barrier(0);                                             \
} while (0)

// One K-tile: read from (LA,LB); if DOST, stage tile KTN into (LAN,LBN).
// Reads issue early; MFMA clusters run behind counted lgkm waits; single
// boundary sync. Cross-wave safety: readers retire reads before their last
// MFMA, hence before the barrier; stages target the opposite buffer only.
#define TILE(LA, LB, LAN, LBN, KTN, DOST) do {                                     \
    RDB(bb0, LB, 0);                                                               \
    RDA(afa, LA, 0, 0);                                                            \
    RDA(afb, LA, 1, 0);                                                            \
    RDB(bb1, LB, 32);                                                              \
    RDA(afc, LA, 0, 32);                                                           \
    if (DOST) {                                                                    \
        STAGE(APAN(0, KTN), LAN);                                                  \
        STAGE(APAN(1, KTN), LAN + 16384);                                          \
        STAGE(BPAN(0, KTN), LBN);                                                  \
        STAGE(BPAN(1, KTN), LBN + 16384);                                          \
    }                                                                              \
    __builtin_amdgcn_sched_barrier(0);                                             \
    MM(0, afa, bb0);                                                               \
    RDA(afd, LA, 1, 32);                                                           \
    MM(1, afb, bb0);                                                               \
    MM(0, afc, bb1);                                                               \
    MM(1, afd, bb1);                                                               \
    asm volatile("s_waitcnt vmcnt(0)" ::: "memory");                               \
    __builtin_amdgcn_sched_barrier(0);                                             \
    __builtin_amdgcn_s_barrier();                                                  \
} while (0)

__global__ __launch_bounds__(512, 2) void gemm256(const char* __restrict__ Xw,
                                                  const char* __restrict__ Ww,
                                                  float* __restrict__ out) {
    __shared__ char lds[131072];
    char* lA0 = lds;
    char* lB0 = lds + 32768;
    char* lA1 = lds + 65536;
    char* lB1 = lds + 98304;

    const int t = threadIdx.x;
    const int wave = t >> 6, lane = t & 63;
    const int wm = wave >> 2, wn = wave & 3;      // 2 x 4 waves, 128x64 per wave
    const int l15 = lane & 15, lhi16 = (lane >> 4) * 16;

    // bijective XCD swizzle (2048 % 8 == 0); n-chunked for B-slab L2 residency
    const int xcd = blockIdx.x & 7;
    const int c   = blockIdx.x >> 3;              // 0..255
    const int bn  = xcd * 8 + (c >> 5);           // 0..63
    const int bm  = c & 31;                       // 0..31
    const int bm2 = bm * 2, bn2 = bn * 2;

    const int woff16 = wave * 1024 + lane * 16;   // per-lane global offset
    const int woffu  = wave * 1024;               // wave-uniform LDS offset
    const int apan = wm * 16384;                  // wave's A half-panel
    const int bpan = (wn >> 1) * 16384;           // wave's B half-panel
    const int brow = (wn & 1) * 64 + l15;         // B row base within panel

    bf16x8 afa[4], afb[4], afc[4], afd[4], bb0[4], bb1[4];
    f32x4 acc[8][4] = {};

    // prologue: stage tile0 into buf0; certify; sync
    STAGE(APAN(0, 0), lA0);
    STAGE(APAN(1, 0), lA0 + 16384);
    STAGE(BPAN(0, 0), lB0);
    STAGE(BPAN(1, 0), lB0 + 16384);
    asm volatile("s_waitcnt vmcnt(0)" ::: "memory");
    __builtin_amdgcn_sched_barrier(0);
    __builtin_amdgcn_s_barrier();

    for (int i = 0; i < 32; ++i) {
        const int kt = 2 * i;
        // even tile (buf0), always stage odd tile kt+1 into buf1
        TILE(lA0, lB0, lA1, lB1, kt + 1, true);
        // odd tile (buf1), stage kt+2 into buf0 unless last
        TILE(lA1, lB1, lA0, lB0, kt + 2, (i < 31));
    }

    // epilogue: C/D layout col=lane&15, row=(lane>>4)*4+reg
    const int gr0 = bm * 256 + wm * 128 + (lhi16 >> 2);
    const int gc0 = bn * 256 + wn * 64 + l15;
    #pragma unroll
    for (int mi = 0; mi < 8; ++mi)
        #pragma unroll
        for (int ni = 0; ni < 4; ++ni)
            #pragma unroll
            for (int rr = 0; rr < 4; ++rr)
                out[(size_t)(gr0 + mi * 16 + rr) * NTOT + gc0 + ni * 16] =
                    acc[mi][ni][rr];
}

// ---------------- Fallback (ws too small): round-1 fused kernel ----------------
#define LDP 72
__global__ __launch_bounds__(256) void int4_gemm(
    const float* __restrict__ x, const int* __restrict__ qw,
    const int* __restrict__ qz, const float* __restrict__ sc,
    float* __restrict__ out)
{
    __shared__ short As[128][LDP];
    __shared__ short Bs[128][LDP];
    const int t = threadIdx.x;
    int gid = (blockIdx.x & 7) * 1024 + (blockIdx.x >> 3);
    const int bm = gid & 63;
    const int bnq = gid >> 6;
    const int kse = bnq >> 6;
    const int f0  = (bnq & 63) * 128;
    const int m0  = bm * 128;
    const int wave = t >> 6, lane = t & 63;
    const int wm = wave >> 1, wn = wave & 1;
    const int l15 = lane & 15, lhi = lane >> 4;
    const int am = t >> 4, ad = (t & 15) * 4;
    const int bf = t & 127, bd = (t >> 7) * 4;
    const int*   qwk = qw + (size_t)kse * Dd * Ff;
    const int*   qzk = qz + (size_t)kse * 32 * Ff;
    const float* sck = sc + (size_t)kse * 32 * Ff;
    f32x4 acc[4][4] = {};
    for (int d0 = 0; d0 < Dd; d0 += 64) {
        __syncthreads();
        #pragma unroll
        for (int p = 0; p < 8; ++p) {
            int m = p * 16 + am;
            const float4 v = *reinterpret_cast<const float4*>(
                &x[(size_t)(m0 + m) * Dd + d0 + ad]);
            short4 wv;
            wv.x = f2bf(v.x); wv.y = f2bf(v.y); wv.z = f2bf(v.z); wv.w = f2bf(v.w);
            *reinterpret_cast<short4*>(&As[m][ad]) = wv;
        }
        {
            const int g = d0 >> 7;
            const int   zv = qzk[g * Ff + f0 + bf];
            const float sv = sck[g * Ff + f0 + bf];
            #pragma unroll
            for (int p = 0; p < 8; ++p) {
                int dl = p * 8 + bd;
                const int* qp = qwk + (size_t)(d0 + dl) * Ff + f0 + bf;
                short4 wv;
                wv.x = f2bf((float)(qp[0]      - zv) * sv);
                wv.y = f2bf((float)(qp[Ff]     - zv) * sv);
                wv.z = f2bf((float)(qp[2 * Ff] - zv) * sv);
                wv.w = f2bf((float)(qp[3 * Ff] - zv) * sv);
                *reinterpret_cast<short4*>(&Bs[bf][dl]) = wv;
            }
        }
        __syncthreads();
        #pragma unroll
        for (int kk = 0; kk < 64; kk += 32) {
            bf16x8 a2[4], b2[4];
            #pragma unroll
            for (int i = 0; i < 4; ++i)
                a2[i] = *reinterpret_cast<const bf16x8*>(&As[wm * 64 + i * 16 + l15][kk + lhi * 8]);
            #pragma unroll
            for (int i = 0; i < 4; ++i)
                b2[i] = *reinterpret_cast<const bf16x8*>(&Bs[wn * 64 + i * 16 + l15][kk + lhi * 8]);
            #pragma unroll
            for (int mi = 0; mi < 4; ++mi)
                #pragma unroll
                for (int ni = 0; ni < 4; ++ni)
                    acc[mi][ni] = __builtin_amdgcn_mfma_f32_16x16x32_bf16(
                        a2[mi], b2[ni], acc[mi][ni], 0, 0, 0);
        }
    }
    const int crow0 = m0 + wm * 64 + lhi * 4;
    const int ccol0 = bnq * 128 + wn * 64 + l15;
    #pragma unroll
    for (int mi = 0; mi < 4; ++mi)
        #pragma unroll
        for (int ni = 0; ni < 4; ++ni)
            #pragma unroll
            for (int r = 0; r < 4; ++r)
                out[(size_t)(crow0 + mi * 16 + r) * NTOT + ccol0 + ni * 16] =
                    acc[mi][ni][r];
}

extern "C" void kernel_launch(void* const* d_in, const int* in_sizes, int n_in,
                              void* d_out, int out_size, void* d_ws, size_t ws_size,
                              hipStream_t stream) {
    const float* x  = (const float*)d_in[0];
    const int*   qw = (const int*)d_in[1];
    const int*   qz = (const int*)d_in[2];
    const float* sc = (const float*)d_in[3];
    float*       out = (float*)d_out;

    const size_t xw_bytes = (size_t)(M / 128) * NKT * 16384;      // 64 MiB
    const size_t ww_bytes = (size_t)(NTOT / 128) * NKT * 16384;   // 128 MiB

    if (ws_size >= xw_bytes + ww_bytes) {
        char* Xw = (char*)d_ws;
        char* Ww = Xw + xw_bytes;
        hipLaunchKernelGGL(xcvt, dim3((M / 128) * NKT), dim3(256), 0, stream, x, Xw);
        hipLaunchKernelGGL(wdq, dim3((NTOT / 128) * NKT), dim3(256), 0, stream,
                           qw, qz, sc, Ww);
        hipLaunchKernelGGL(gemm256, dim3(NMB * NNB), dim3(512), 0, stream,
                           Xw, Ww, out);
    } else {
        hipLaunchKernelGGL(int4_gemm, dim3(8192), dim3(256), 0, stream,
                           x, qw, qz, sc, out);
    }
}

// Round 7
// 1238.296 us; speedup vs baseline: 1.2114x; 1.1916x over previous
//
#include <hip/hip_runtime.h>
#include <hip/hip_bf16.h>
#include <stdint.h>

// out[b,t,k,f] = sum_d x[b,t,d] * (qw[k,d,f]-qz[k,d/128,f])*sc[k,d/128,f]
// Stage 1: swizzled bf16 panels in d_ws (A: [m_half][kt], B^T: [n_half][kt],
//          16KB panels, byte (r*128+c*2)^((r&7)<<4)).
// Stage 2: 256x256x64 8-phase double-buffered GEMM — R4's exact schedule
//          (best measured: 50% MfmaUtil), MFMA switched 16x16x32 -> 32x32x16
//          (2382 vs 2075 TF ceiling, half the instruction count).
// R5/R6 lesson: do not restructure the sync skeleton; per-phase barriers +
// counted vmcnt(2) at P4/P8 is the proven schedule.

typedef __attribute__((ext_vector_type(8))) short bf16x8;
typedef __attribute__((ext_vector_type(16))) float f32x16;
typedef __attribute__((ext_vector_type(4))) float f32x4;

static constexpr int Dd = 4096, Ff = 8192;
static constexpr int M = 8192, NTOT = 16384;
static constexpr int NKT = Dd / 64;       // 64 K-tiles
static constexpr int NMB = M / 256;       // 32
static constexpr int NNB = NTOT / 256;    // 64

__device__ __forceinline__ short f2bf(float f) {
    __hip_bfloat16 h = __float2bfloat16(f);
    return *reinterpret_cast<short*>(&h);
}

// ---------------- Stage 1a: x fp32 -> swizzled bf16 A-panels ----------------
__global__ __launch_bounds__(256) void xcvt(const float* __restrict__ x,
                                            char* __restrict__ Xw) {
    const int bid = blockIdx.x;             // h*64 + kt, h in [0,64)
    const int h = bid >> 6, kt = bid & 63;
    const int t = threadIdx.x;
    const int r = t >> 1, seg = t & 1;
    const float* src = x + ((size_t)(h * 128 + r)) * Dd + kt * 64 + seg * 32;
    char* panel = Xw + ((size_t)bid << 14);
    #pragma unroll
    for (int jj = 0; jj < 4; ++jj) {
        float4 v0 = *reinterpret_cast<const float4*>(src + jj * 8);
        float4 v1 = *reinterpret_cast<const float4*>(src + jj * 8 + 4);
        union { short s[8]; bf16x8 v; } u;
        u.s[0] = f2bf(v0.x); u.s[1] = f2bf(v0.y); u.s[2] = f2bf(v0.z); u.s[3] = f2bf(v0.w);
        u.s[4] = f2bf(v1.x); u.s[5] = f2bf(v1.y); u.s[6] = f2bf(v1.z); u.s[7] = f2bf(v1.w);
        const int cb = seg * 4 + jj;
        const int g = r * 8 + (cb ^ (r & 7));
        *reinterpret_cast<bf16x8*>(panel + g * 16) = u.v;
    }
}

// ---------------- Stage 1b: dequant int4 -> swizzled bf16 B^T panels ----------------
__global__ __launch_bounds__(256) void wdq(const int* __restrict__ qw,
                                           const int* __restrict__ qz,
                                           const float* __restrict__ sc,
                                           char* __restrict__ Ww) {
    const int bid = blockIdx.x;             // fh*64 + kt, fh in [0,128)
    const int fh = bid >> 6, kt = bid & 63;
    const int t = threadIdx.x;
    const int r = t & 127, dh = t >> 7;
    const int n = fh * 128 + r;
    const int k = n >> 13, f = n & 8191;
    const int g = kt >> 1;                  // 64-col tile within one 128-group
    const int   zv = qz[((size_t)k * 32 + g) * Ff + f];
    const float sv = sc[((size_t)k * 32 + g) * Ff + f];
    const int* qp = qw + ((size_t)(k * Dd + kt * 64 + dh * 32)) * Ff + f;
    char* panel = Ww + ((size_t)bid << 14);
    #pragma unroll
    for (int jj = 0; jj < 4; ++jj) {
        union { short s[8]; bf16x8 v; } u;
        #pragma unroll
        for (int e = 0; e < 8; ++e) {
            int q = qp[(size_t)(jj * 8 + e) * Ff];
            u.s[e] = f2bf((float)(q - zv) * sv);
        }
        const int cb = dh * 4 + jj;
        const int gi = r * 8 + (cb ^ (r & 7));
        *reinterpret_cast<bf16x8*>(panel + gi * 16) = u.v;
    }
}

// ---------------- Stage 2: 256x256 8-phase GEMM (32x32x16 MFMA) ----------------
#define APAN(HALF, KT) (Xw + (((size_t)(bm2 + (HALF)) * 64 + (KT)) << 14))
#define BPAN(HALF, KT) (Ww + (((size_t)(bn2 + (HALF)) * 64 + (KT)) << 14))

#define STAGE(GP, LP) do {                                                         \
    const char* _g = (GP) + woff16;                                                \
    char* _l = (LP) + woffu;                                                       \
    __builtin_amdgcn_global_load_lds(                                              \
        (const __attribute__((address_space(1))) void*)(_g),                       \
        (__attribute__((address_space(3))) void*)(_l), 16, 0, 0);                  \
    __builtin_amdgcn_global_load_lds(                                              \
        (const __attribute__((address_space(1))) void*)(_g + 8192),                \
        (__attribute__((address_space(3))) void*)(_l + 8192), 16, 0, 0);           \
} while (0)

// swizzled LDS read of one MFMA fragment (16B); R in rows, CB in bytes
#define RDF(BASE, R, CB) \
    (*reinterpret_cast<const bf16x8*>((BASE) + ((((R) << 7) + (CB)) ^ (((R) & 7) << 4))))

// Phase (H = m-half of wave tile, KS2 = k-step pair base 0|2), 8 x 32x32x16 MFMA.
// A frag (mf,ks): row mf*32+l31, bytes ks*32+lh16 ; B frag (nf,ks): row brow+nf*32.
#define PHASE(LA, LB, H, KS2, LOADB, STG, WAITQ) do {                              \
    if (LOADB) {                                                                   \
        _Pragma("unroll")                                                          \
        for (int nf = 0; nf < 2; ++nf)                                             \
            _Pragma("unroll")                                                      \
            for (int kq = 0; kq < 2; ++kq)                                         \
                bb[nf * 2 + kq] = RDF((LB) + bpan, brow + nf * 32,                 \
                                      ((KS2) + kq) * 32 + lh16);                   \
    }                                                                              \
    _Pragma("unroll")                                                              \
    for (int mf = 0; mf < 2; ++mf)                                                 \
        _Pragma("unroll")                                                          \
        for (int kq = 0; kq < 2; ++kq)                                             \
            af[mf * 2 + kq] = RDF((LA) + apan, ((H) * 2 + mf) * 32 + l31,          \
                                  ((KS2) + kq) * 32 + lh16);                       \
    STG;                                                                           \
    __builtin_amdgcn_sched_barrier(0);                                             \
    __builtin_amdgcn_s_barrier();                                                  \
    asm volatile("s_waitcnt lgkmcnt(0)" ::: "memory");                             \
    __builtin_amdgcn_sched_barrier(0);                                             \
    __builtin_amdgcn_s_setprio(1);                                                 \
    _Pragma("unroll")                                                              \
    for (int kq = 0; kq < 2; ++kq)                                                 \
        _Pragma("unroll")                                                          \
        for (int mf = 0; mf < 2; ++mf)                                             \
            _Pragma("unroll")                                                      \
            for (int nf = 0; nf < 2; ++nf)                                         \
                acc[((H) * 2 + mf) * 2 + nf] = __builtin_amdgcn_mfma_f32_32x32x16_bf16( \
                    af[mf * 2 + kq], bb[nf * 2 + kq],                              \
                    acc[((H) * 2 + mf) * 2 + nf], 0, 0, 0);                        \
    __builtin_amdgcn_s_setprio(0);                                                 \
    WAITQ;                                                                         \
    __builtin_amdgcn_sched_barrier(0);                                             \
    __builtin_amdgcn_s_barrier();                                                  \
} while (0)

__global__ __launch_bounds__(512, 2) void gemm256(const char* __restrict__ Xw,
                                                  const char* __restrict__ Ww,
                                                  float* __restrict__ out) {
    __shared__ char lds[131072];
    char* lA0 = lds;
    char* lB0 = lds + 32768;
    char* lA1 = lds + 65536;
    char* lB1 = lds + 98304;

    const int t = threadIdx.x;
    const int wave = t >> 6, lane = t & 63;
    const int wm = wave >> 2, wn = wave & 3;      // 2 x 4 waves, 128x64 per wave
    const int l31 = lane & 31;
    const int lh16 = (lane >> 5) * 16;            // k-half byte offset

    // bijective XCD swizzle (2048 % 8 == 0); n-chunked for B-slab L2 residency
    const int xcd = blockIdx.x & 7;
    const int c   = blockIdx.x >> 3;              // 0..255
    const int bn  = xcd * 8 + (c >> 5);           // 0..63
    const int bm  = c & 31;                       // 0..31
    const int bm2 = bm * 2, bn2 = bn * 2;

    const int woff16 = wave * 1024 + lane * 16;   // per-lane global offset
    const int woffu  = wave * 1024;               // wave-uniform LDS offset
    const int apan = wm * 16384;                  // wave's A half-panel
    const int bpan = (wn >> 1) * 16384;           // wave's B half-panel
    const int brow = (wn & 1) * 64 + l31;         // B row base within panel

    bf16x8 af[4], bb[4];
    f32x16 acc[8] = {};   // [mf 0..3][nf 0..1]

    // prologue: tile0 (4 halves) + tile1.B0; wait tile0; sync
    STAGE(APAN(0, 0), lA0);
    STAGE(APAN(1, 0), lA0 + 16384);
    STAGE(BPAN(0, 0), lB0);
    STAGE(BPAN(1, 0), lB0 + 16384);
    STAGE(BPAN(0, 1), lB1);
    asm volatile("s_waitcnt vmcnt(2)" ::: "memory");
    __builtin_amdgcn_sched_barrier(0);
    __builtin_amdgcn_s_barrier();

    for (int i = 0; i < 32; ++i) {
        const int kt0 = 2 * i;
        const bool nl = (i < 31);
        // tile kt0 from buf0; stage rest of tile kt0+1 into buf1, then kt0+2.B0
        PHASE(lA0, lB0, 0, 0, 1, { STAGE(BPAN(1, kt0 + 1), lB1 + 16384); }, );
        PHASE(lA0, lB0, 1, 0, 0, { STAGE(APAN(0, kt0 + 1), lA1); }, );
        PHASE(lA0, lB0, 0, 2, 1, { STAGE(APAN(1, kt0 + 1), lA1 + 16384); }, );
        PHASE(lA0, lB0, 1, 2, 0, { if (nl) STAGE(BPAN(0, kt0 + 2), lB0); },
              { if (nl) asm volatile("s_waitcnt vmcnt(2)" ::: "memory");
                else    asm volatile("s_waitcnt vmcnt(0)" ::: "memory"); });
        // tile kt0+1 from buf1; stage kt0+2 rest into buf0, kt0+3.B0 into buf1
        PHASE(lA1, lB1, 0, 0, 1, { if (nl) STAGE(BPAN(1, kt0 + 2), lB0 + 16384); }, );
        PHASE(lA1, lB1, 1, 0, 0, { if (nl) STAGE(APAN(0, kt0 + 2), lA0); }, );
        PHASE(lA1, lB1, 0, 2, 1, { if (nl) STAGE(APAN(1, kt0 + 2), lA0 + 16384); }, );
        PHASE(lA1, lB1, 1, 2, 0, { if (nl) STAGE(BPAN(0, kt0 + 3), lB1); },
              { if (nl) asm volatile("s_waitcnt vmcnt(2)" ::: "memory");
                else    asm volatile("s_waitcnt vmcnt(0)" ::: "memory"); });
    }

    // epilogue: 32x32 C/D layout: col=lane&31, row=(reg&3)+8*(reg>>2)+4*(lane>>5)
    const int rbase = bm * 256 + wm * 128 + (lane >> 5) * 4;
    const int cbase = bn * 256 + wn * 64 + l31;
    #pragma unroll
    for (int mf = 0; mf < 4; ++mf)
        #pragma unroll
        for (int nf = 0; nf < 2; ++nf)
            #pragma unroll
            for (int reg = 0; reg < 16; ++reg) {
                const int row = rbase + mf * 32 + (reg & 3) + 8 * (reg >> 2);
                out[(size_t)row * NTOT + cbase + nf * 32] = acc[mf * 2 + nf][reg];
            }
}

// ---------------- Fallback (ws too small): round-1 fused kernel ----------------
#define LDP 72
__global__ __launch_bounds__(256) void int4_gemm(
    const float* __restrict__ x, const int* __restrict__ qw,
    const int* __restrict__ qz, const float* __restrict__ sc,
    float* __restrict__ out)
{
    __shared__ short As[128][LDP];
    __shared__ short Bs[128][LDP];
    const int t = threadIdx.x;
    int gid = (blockIdx.x & 7) * 1024 + (blockIdx.x >> 3);
    const int bm = gid & 63;
    const int bnq = gid >> 6;
    const int kse = bnq >> 6;
    const int f0  = (bnq & 63) * 128;
    const int m0  = bm * 128;
    const int wave = t >> 6, lane = t & 63;
    const int wm = wave >> 1, wn = wave & 1;
    const int l15 = lane & 15, lhi = lane >> 4;
    const int am = t >> 4, ad = (t & 15) * 4;
    const int bf = t & 127, bd = (t >> 7) * 4;
    const int*   qwk = qw + (size_t)kse * Dd * Ff;
    const int*   qzk = qz + (size_t)kse * 32 * Ff;
    const float* sck = sc + (size_t)kse * 32 * Ff;
    f32x4 acc[4][4] = {};
    for (int d0 = 0; d0 < Dd; d0 += 64) {
        __syncthreads();
        #pragma unroll
        for (int p = 0; p < 8; ++p) {
            int m = p * 16 + am;
            const float4 v = *reinterpret_cast<const float4*>(
                &x[(size_t)(m0 + m) * Dd + d0 + ad]);
            short4 wv;
            wv.x = f2bf(v.x); wv.y = f2bf(v.y); wv.z = f2bf(v.z); wv.w = f2bf(v.w);
            *reinterpret_cast<short4*>(&As[m][ad]) = wv;
        }
        {
            const int g = d0 >> 7;
            const int   zv = qzk[g * Ff + f0 + bf];
            const float sv = sck[g * Ff + f0 + bf];
            #pragma unroll
            for (int p = 0; p < 8; ++p) {
                int dl = p * 8 + bd;
                const int* qp = qwk + (size_t)(d0 + dl) * Ff + f0 + bf;
                short4 wv;
                wv.x = f2bf((float)(qp[0]      - zv) * sv);
                wv.y = f2bf((float)(qp[Ff]     - zv) * sv);
                wv.z = f2bf((float)(qp[2 * Ff] - zv) * sv);
                wv.w = f2bf((float)(qp[3 * Ff] - zv) * sv);
                *reinterpret_cast<short4*>(&Bs[bf][dl]) = wv;
            }
        }
        __syncthreads();
        #pragma unroll
        for (int kk = 0; kk < 64; kk += 32) {
            bf16x8 a2[4], b2[4];
            #pragma unroll
            for (int i = 0; i < 4; ++i)
                a2[i] = *reinterpret_cast<const bf16x8*>(&As[wm * 64 + i * 16 + l15][kk + lhi * 8]);
            #pragma unroll
            for (int i = 0; i < 4; ++i)
                b2[i] = *reinterpret_cast<const bf16x8*>(&Bs[wn * 64 + i * 16 + l15][kk + lhi * 8]);
            #pragma unroll
            for (int mi = 0; mi < 4; ++mi)
                #pragma unroll
                for (int ni = 0; ni < 4; ++ni)
                    acc[mi][ni] = __builtin_amdgcn_mfma_f32_16x16x32_bf16(
                        a2[mi], b2[ni], acc[mi][ni], 0, 0, 0);
        }
    }
    const int crow0 = m0 + wm * 64 + lhi * 4;
    const int ccol0 = bnq * 128 + wn * 64 + l15;
    #pragma unroll
    for (int mi = 0; mi < 4; ++mi)
        #pragma unroll
        for (int ni = 0; ni < 4; ++ni)
            #pragma unroll
            for (int r = 0; r < 4; ++r)
                out[(size_t)(crow0 + mi * 16 + r) * NTOT + ccol0 + ni * 16] =
                    acc[mi][ni][r];
}

extern "C" void kernel_launch(void* const* d_in, const int* in_sizes, int n_in,
                              void* d_out, int out_size, void* d_ws, size_t ws_size,
                              hipStream_t stream) {
    const float* x  = (const float*)d_in[0];
    const int*   qw = (const int*)d_in[1];
    const int*   qz = (const int*)d_in[2];
    const float* sc = (const float*)d_in[3];
    float*       out = (float*)d_out;

    const size_t xw_bytes = (size_t)(M / 128) * NKT * 16384;      // 64 MiB
    const size_t ww_bytes = (size_t)(NTOT / 128) * NKT * 16384;   // 128 MiB

    if (ws_size >= xw_bytes + ww_bytes) {
        char* Xw = (char*)d_ws;
        char* Ww = Xw + xw_bytes;
        hipLaunchKernelGGL(xcvt, dim3((M / 128) * NKT), dim3(256), 0, stream, x, Xw);
        hipLaunchKernelGGL(wdq, dim3((NTOT / 128) * NKT), dim3(256), 0, stream,
                           qw, qz, sc, Ww);
        hipLaunchKernelGGL(gemm256, dim3(NMB * NNB), dim3(512), 0, stream,
                           Xw, Ww, out);
    } else {
        hipLaunchKernelGGL(int4_gemm, dim3(8192), dim3(256), 0, stream,
                           x, qw, qz, sc, out);
    }
}

// Round 8
// 1146.125 us; speedup vs baseline: 1.3088x; 1.0804x over previous
//
#include <hip/hip_runtime.h>
#include <hip/hip_bf16.h>
#include <stdint.h>

// out[b,t,k,f] = sum_d x[b,t,d] * (qw[k,d,f]-qz[k,d/128,f])*sc[k,d/128,f]
// Stage 1: FRAGMENT-LINEAR bf16 panels in d_ws. Panel = 128 rows x 64 k = 16KB,
//   split into 16 fragments of 1KB: frag(rb,ks), rb=row-block of 32, ks=k-step
//   of 16. Within a fragment, byte l*16 holds row rb*32+(l&31),
//   k = ks*16 + (l>>5)*8 .. +8  — exactly lane l's mfma_32x32x16 operand slice.
//   => every LDS fragment read is a linear 1024B ds_read_b128 burst at
//      base + lane*16: zero bank conflicts, zero address VALU. No swizzle.
// Stage 2: 256x256x64 8-phase double-buffered GEMM (R4's proven schedule),
//   mfma_f32_32x32x16_bf16.
// R7 lesson: 32-row fragment reads through the (r&7)<<4 XOR layout are 4-way
// bank-conflicted (1e8 extra cycles = the whole MFMA-rate gain). Layout must
// match the fragment geometry; with writer-controlled panels, make it linear.

typedef __attribute__((ext_vector_type(8))) short bf16x8;
typedef __attribute__((ext_vector_type(16))) float f32x16;
typedef __attribute__((ext_vector_type(4))) float f32x4;

static constexpr int Dd = 4096, Ff = 8192;
static constexpr int M = 8192, NTOT = 16384;
static constexpr int NKT = Dd / 64;       // 64 K-tiles
static constexpr int NMB = M / 256;       // 32
static constexpr int NNB = NTOT / 256;    // 64

__device__ __forceinline__ short f2bf(float f) {
    __hip_bfloat16 h = __float2bfloat16(f);
    return *reinterpret_cast<short*>(&h);
}

// fragment-linear byte offset within a 16KB panel: row r (0..127), 8-elem
// k-group cb (0..7; k = cb*8..cb*8+8)
__device__ __forceinline__ int frag_off(int r, int cb) {
    const int rb = r >> 5, ks = cb >> 1, kh = cb & 1;
    return ((rb * 4 + ks) << 10) + (((r & 31) + 32 * kh) << 4);
}

// ---------------- Stage 1a: x fp32 -> fragment-linear bf16 A-panels ----------------
__global__ __launch_bounds__(256) void xcvt(const float* __restrict__ x,
                                            char* __restrict__ Xw) {
    const int bid = blockIdx.x;             // h*64 + kt, h in [0,64)
    const int h = bid >> 6, kt = bid & 63;
    const int t = threadIdx.x;
    const int r = t >> 1, seg = t & 1;
    const float* src = x + ((size_t)(h * 128 + r)) * Dd + kt * 64 + seg * 32;
    char* panel = Xw + ((size_t)bid << 14);
    #pragma unroll
    for (int jj = 0; jj < 4; ++jj) {
        float4 v0 = *reinterpret_cast<const float4*>(src + jj * 8);
        float4 v1 = *reinterpret_cast<const float4*>(src + jj * 8 + 4);
        union { short s[8]; bf16x8 v; } u;
        u.s[0] = f2bf(v0.x); u.s[1] = f2bf(v0.y); u.s[2] = f2bf(v0.z); u.s[3] = f2bf(v0.w);
        u.s[4] = f2bf(v1.x); u.s[5] = f2bf(v1.y); u.s[6] = f2bf(v1.z); u.s[7] = f2bf(v1.w);
        const int cb = seg * 4 + jj;        // k = cb*8 .. +8
        *reinterpret_cast<bf16x8*>(panel + frag_off(r, cb)) = u.v;
    }
}

// ---------------- Stage 1b: dequant int4 -> fragment-linear bf16 B^T panels ----------------
__global__ __launch_bounds__(256) void wdq(const int* __restrict__ qw,
                                           const int* __restrict__ qz,
                                           const float* __restrict__ sc,
                                           char* __restrict__ Ww) {
    const int bid = blockIdx.x;             // fh*64 + kt, fh in [0,128)
    const int fh = bid >> 6, kt = bid & 63;
    const int t = threadIdx.x;
    const int r = t & 127, dh = t >> 7;
    const int n = fh * 128 + r;
    const int k = n >> 13, f = n & 8191;
    const int g = kt >> 1;                  // 64-col tile within one 128-group
    const int   zv = qz[((size_t)k * 32 + g) * Ff + f];
    const float sv = sc[((size_t)k * 32 + g) * Ff + f];
    const int* qp = qw + ((size_t)(k * Dd + kt * 64 + dh * 32)) * Ff + f;
    char* panel = Ww + ((size_t)bid << 14);
    #pragma unroll
    for (int jj = 0; jj < 4; ++jj) {
        union { short s[8]; bf16x8 v; } u;
        #pragma unroll
        for (int e = 0; e < 8; ++e) {
            int q = qp[(size_t)(jj * 8 + e) * Ff];
            u.s[e] = f2bf((float)(q - zv) * sv);
        }
        const int cb = dh * 4 + jj;         // k = cb*8 .. +8
        *reinterpret_cast<bf16x8*>(panel + frag_off(r, cb)) = u.v;
    }
}

// ---------------- Stage 2: 256x256 8-phase GEMM (32x32x16 MFMA) ----------------
#define APAN(HALF, KT) (Xw + (((size_t)(bm2 + (HALF)) * 64 + (KT)) << 14))
#define BPAN(HALF, KT) (Ww + (((size_t)(bn2 + (HALF)) * 64 + (KT)) << 14))

#define STAGE(GP, LP) do {                                                         \
    const char* _g = (GP) + woff16;                                                \
    char* _l = (LP) + woffu;                                                       \
    __builtin_amdgcn_global_load_lds(                                              \
        (const __attribute__((address_space(1))) void*)(_g),                       \
        (__attribute__((address_space(3))) void*)(_l), 16, 0, 0);                  \
    __builtin_amdgcn_global_load_lds(                                              \
        (const __attribute__((address_space(1))) void*)(_g + 8192),                \
        (__attribute__((address_space(3))) void*)(_l + 8192), 16, 0, 0);           \
} while (0)

// Phase (H = m-half of wave tile, KS2 = k-step pair base 0|2): 8 x 32x32x16 MFMA.
// All fragment reads are linear: base + frag_index*1024 + lane*16.
#define PHASE(LA, LB, H, KS2, LOADB, STG, WAITQ) do {                              \
    if (LOADB) {                                                                   \
        _Pragma("unroll")                                                          \
        for (int nf = 0; nf < 2; ++nf)                                             \
            _Pragma("unroll")                                                      \
            for (int kq = 0; kq < 2; ++kq)                                         \
                bb[nf * 2 + kq] = *reinterpret_cast<const bf16x8*>(                \
                    (LB) + bbase + ((nf * 4 + (KS2) + kq) << 10) + lane16);        \
    }                                                                              \
    _Pragma("unroll")                                                              \
    for (int mf = 0; mf < 2; ++mf)                                                 \
        _Pragma("unroll")                                                          \
        for (int kq = 0; kq < 2; ++kq)                                             \
            af[mf * 2 + kq] = *reinterpret_cast<const bf16x8*>(                    \
                (LA) + abase + (((((H) * 2 + mf) * 4) + (KS2) + kq) << 10) + lane16); \
    STG;                                                                           \
    __builtin_amdgcn_sched_barrier(0);                                             \
    __builtin_amdgcn_s_barrier();                                                  \
    asm volatile("s_waitcnt lgkmcnt(0)" ::: "memory");                             \
    __builtin_amdgcn_sched_barrier(0);                                             \
    __builtin_amdgcn_s_setprio(1);                                                 \
    _Pragma("unroll")                                                              \
    for (int kq = 0; kq < 2; ++kq)                                                 \
        _Pragma("unroll")                                                          \
        for (int mf = 0; mf < 2; ++mf)                                             \
            _Pragma("unroll")                                                      \
            for (int nf = 0; nf < 2; ++nf)                                         \
                acc[((H) * 2 + mf) * 2 + nf] = __builtin_amdgcn_mfma_f32_32x32x16_bf16( \
                    af[mf * 2 + kq], bb[nf * 2 + kq],                              \
                    acc[((H) * 2 + mf) * 2 + nf], 0, 0, 0);                        \
    __builtin_amdgcn_s_setprio(0);                                                 \
    WAITQ;                                                                         \
    __builtin_amdgcn_sched_barrier(0);                                             \
    __builtin_amdgcn_s_barrier();                                                  \
} while (0)

__global__ __launch_bounds__(512, 2) void gemm256(const char* __restrict__ Xw,
                                                  const char* __restrict__ Ww,
                                                  float* __restrict__ out) {
    __shared__ char lds[131072];
    char* lA0 = lds;
    char* lB0 = lds + 32768;
    char* lA1 = lds + 65536;
    char* lB1 = lds + 98304;

    const int t = threadIdx.x;
    const int wave = t >> 6, lane = t & 63;
    const int wm = wave >> 2, wn = wave & 3;      // 2 x 4 waves, 128x64 per wave
    const int l31 = lane & 31;
    const int lane16 = lane << 4;

    // bijective XCD swizzle (2048 % 8 == 0); n-chunked for B-slab L2 residency
    const int xcd = blockIdx.x & 7;
    const int c   = blockIdx.x >> 3;              // 0..255
    const int bn  = xcd * 8 + (c >> 5);           // 0..63
    const int bm  = c & 31;                       // 0..31
    const int bm2 = bm * 2, bn2 = bn * 2;

    const int woff16 = wave * 1024 + lane16;      // per-lane global offset
    const int woffu  = wave * 1024;               // wave-uniform LDS offset
    const int abase = wm * 16384;                 // wave's A panel (128 rows)
    const int bbase = (wn >> 1) * 16384 + (wn & 1) * 8192;  // wave's 64-row B slab

    bf16x8 af[4], bb[4];
    f32x16 acc[8] = {};   // [mf 0..3][nf 0..1]

    // prologue: tile0 (4 halves) + tile1.B0; wait tile0; sync
    STAGE(APAN(0, 0), lA0);
    STAGE(APAN(1, 0), lA0 + 16384);
    STAGE(BPAN(0, 0), lB0);
    STAGE(BPAN(1, 0), lB0 + 16384);
    STAGE(BPAN(0, 1), lB1);
    asm volatile("s_waitcnt vmcnt(2)" ::: "memory");
    __builtin_amdgcn_sched_barrier(0);
    __builtin_amdgcn_s_barrier();

    for (int i = 0; i < 32; ++i) {
        const int kt0 = 2 * i;
        const bool nl = (i < 31);
        // tile kt0 from buf0; stage rest of tile kt0+1 into buf1, then kt0+2.B0
        PHASE(lA0, lB0, 0, 0, 1, { STAGE(BPAN(1, kt0 + 1), lB1 + 16384); }, );
        PHASE(lA0, lB0, 1, 0, 0, { STAGE(APAN(0, kt0 + 1), lA1); }, );
        PHASE(lA0, lB0, 0, 2, 1, { STAGE(APAN(1, kt0 + 1), lA1 + 16384); }, );
        PHASE(lA0, lB0, 1, 2, 0, { if (nl) STAGE(BPAN(0, kt0 + 2), lB0); },
              { if (nl) asm volatile("s_waitcnt vmcnt(2)" ::: "memory");
                else    asm volatile("s_waitcnt vmcnt(0)" ::: "memory"); });
        // tile kt0+1 from buf1; stage kt0+2 rest into buf0, kt0+3.B0 into buf1
        PHASE(lA1, lB1, 0, 0, 1, { if (nl) STAGE(BPAN(1, kt0 + 2), lB0 + 16384); }, );
        PHASE(lA1, lB1, 1, 0, 0, { if (nl) STAGE(APAN(0, kt0 + 2), lA0); }, );
        PHASE(lA1, lB1, 0, 2, 1, { if (nl) STAGE(APAN(1, kt0 + 2), lA0 + 16384); }, );
        PHASE(lA1, lB1, 1, 2, 0, { if (nl) STAGE(BPAN(0, kt0 + 3), lB1); },
              { if (nl) asm volatile("s_waitcnt vmcnt(2)" ::: "memory");
                else    asm volatile("s_waitcnt vmcnt(0)" ::: "memory"); });
    }

    // epilogue: 32x32 C/D layout: col=lane&31, row=(reg&3)+8*(reg>>2)+4*(lane>>5)
    const int rbase = bm * 256 + wm * 128 + (lane >> 5) * 4;
    const int cbase = bn * 256 + wn * 64 + l31;
    #pragma unroll
    for (int mf = 0; mf < 4; ++mf)
        #pragma unroll
        for (int nf = 0; nf < 2; ++nf)
            #pragma unroll
            for (int reg = 0; reg < 16; ++reg) {
                const int row = rbase + mf * 32 + (reg & 3) + 8 * (reg >> 2);
                out[(size_t)row * NTOT + cbase + nf * 32] = acc[mf * 2 + nf][reg];
            }
}

// ---------------- Fallback (ws too small): round-1 fused kernel ----------------
#define LDP 72
__global__ __launch_bounds__(256) void int4_gemm(
    const float* __restrict__ x, const int* __restrict__ qw,
    const int* __restrict__ qz, const float* __restrict__ sc,
    float* __restrict__ out)
{
    __shared__ short As[128][LDP];
    __shared__ short Bs[128][LDP];
    const int t = threadIdx.x;
    int gid = (blockIdx.x & 7) * 1024 + (blockIdx.x >> 3);
    const int bm = gid & 63;
    const int bnq = gid >> 6;
    const int kse = bnq >> 6;
    const int f0  = (bnq & 63) * 128;
    const int m0  = bm * 128;
    const int wave = t >> 6, lane = t & 63;
    const int wm = wave >> 1, wn = wave & 1;
    const int l15 = lane & 15, lhi = lane >> 4;
    const int am = t >> 4, ad = (t & 15) * 4;
    const int bf = t & 127, bd = (t >> 7) * 4;
    const int*   qwk = qw + (size_t)kse * Dd * Ff;
    const int*   qzk = qz + (size_t)kse * 32 * Ff;
    const float* sck = sc + (size_t)kse * 32 * Ff;
    f32x4 acc[4][4] = {};
    for (int d0 = 0; d0 < Dd; d0 += 64) {
        __syncthreads();
        #pragma unroll
        for (int p = 0; p < 8; ++p) {
            int m = p * 16 + am;
            const float4 v = *reinterpret_cast<const float4*>(
                &x[(size_t)(m0 + m) * Dd + d0 + ad]);
            short4 wv;
            wv.x = f2bf(v.x); wv.y = f2bf(v.y); wv.z = f2bf(v.z); wv.w = f2bf(v.w);
            *reinterpret_cast<short4*>(&As[m][ad]) = wv;
        }
        {
            const int g = d0 >> 7;
            const int   zv = qzk[g * Ff + f0 + bf];
            const float sv = sck[g * Ff + f0 + bf];
            #pragma unroll
            for (int p = 0; p < 8; ++p) {
                int dl = p * 8 + bd;
                const int* qp = qwk + (size_t)(d0 + dl) * Ff + f0 + bf;
                short4 wv;
                wv.x = f2bf((float)(qp[0]      - zv) * sv);
                wv.y = f2bf((float)(qp[Ff]     - zv) * sv);
                wv.z = f2bf((float)(qp[2 * Ff] - zv) * sv);
                wv.w = f2bf((float)(qp[3 * Ff] - zv) * sv);
                *reinterpret_cast<short4*>(&Bs[bf][dl]) = wv;
            }
        }
        __syncthreads();
        #pragma unroll
        for (int kk = 0; kk < 64; kk += 32) {
            bf16x8 a2[4], b2[4];
            #pragma unroll
            for (int i = 0; i < 4; ++i)
                a2[i] = *reinterpret_cast<const bf16x8*>(&As[wm * 64 + i * 16 + l15][kk + lhi * 8]);
            #pragma unroll
            for (int i = 0; i < 4; ++i)
                b2[i] = *reinterpret_cast<const bf16x8*>(&Bs[wn * 64 + i * 16 + l15][kk + lhi * 8]);
            #pragma unroll
            for (int mi = 0; mi < 4; ++mi)
                #pragma unroll
                for (int ni = 0; ni < 4; ++ni)
                    acc[mi][ni] = __builtin_amdgcn_mfma_f32_16x16x32_bf16(
                        a2[mi], b2[ni], acc[mi][ni], 0, 0, 0);
        }
    }
    const int crow0 = m0 + wm * 64 + lhi * 4;
    const int ccol0 = bnq * 128 + wn * 64 + l15;
    #pragma unroll
    for (int mi = 0; mi < 4; ++mi)
        #pragma unroll
        for (int ni = 0; ni < 4; ++ni)
            #pragma unroll
            for (int r = 0; r < 4; ++r)
                out[(size_t)(crow0 + mi * 16 + r) * NTOT + ccol0 + ni * 16] =
                    acc[mi][ni][r];
}

extern "C" void kernel_launch(void* const* d_in, const int* in_sizes, int n_in,
                              void* d_out, int out_size, void* d_ws, size_t ws_size,
                              hipStream_t stream) {
    const float* x  = (const float*)d_in[0];
    const int*   qw = (const int*)d_in[1];
    const int*   qz = (const int*)d_in[2];
    const float* sc = (const float*)d_in[3];
    float*       out = (float*)d_out;

    const size_t xw_bytes = (size_t)(M / 128) * NKT * 16384;      // 64 MiB
    const size_t ww_bytes = (size_t)(NTOT / 128) * NKT * 16384;   // 128 MiB

    if (ws_size >= xw_bytes + ww_bytes) {
        char* Xw = (char*)d_ws;
        char* Ww = Xw + xw_bytes;
        hipLaunchKernelGGL(xcvt, dim3((M / 128) * NKT), dim3(256), 0, stream, x, Xw);
        hipLaunchKernelGGL(wdq, dim3((NTOT / 128) * NKT), dim3(256), 0, stream,
                           qw, qz, sc, Ww);
        hipLaunchKernelGGL(gemm256, dim3(NMB * NNB), dim3(512), 0, stream,
                           Xw, Ww, out);
    } else {
        hipLaunchKernelGGL(int4_gemm, dim3(8192), dim3(256), 0, stream,
                           x, qw, qz, sc, out);
    }
}